// Round 1
// baseline (277.195 us; speedup 1.0000x reference)
//
#include <hip/hip_runtime.h>
#include <hip/hip_bf16.h>

#define NUM_FIELDS 39
#define PER_FIELD_VOCAB 10000
#define EMBED_DIM 128
#define KPAD 64          // F padded to 64 for K-chunks of 32
#define NL 5             // 2 (W0) + 3 (W1) interaction slabs
#define RANK 128
#define BATCH 2048
#define LDS_STRIDE 72    // eT row stride in bf16 elems: 64 + 8 pad -> 144 B, 16B-aligned

typedef __bf16  bf16x8  __attribute__((ext_vector_type(8)));
typedef float   f32x4   __attribute__((ext_vector_type(4)));

// ---------------------------------------------------------------------------
// Precompute: W0 [2,128,39] f32, W1 [3,128,39] f32  ->  Wb [5][128][64] bf16
// (zero-padded in f; re-run every launch since d_ws is re-poisoned)
// ---------------------------------------------------------------------------
__global__ __launch_bounds__(256) void prep_w(const float* __restrict__ W0,
                                              const float* __restrict__ W1,
                                              __bf16* __restrict__ Wb) {
    int i = blockIdx.x * 256 + threadIdx.x;       // 5*128*64 = 40960 total
    if (i >= NL * RANK * KPAD) return;
    int f = i & (KPAD - 1);
    int r = (i >> 6) & (RANK - 1);
    int l = i >> 13;
    float v = 0.f;
    if (f < NUM_FIELDS) {
        if (l < 2) v = W0[(l * RANK + r) * NUM_FIELDS + f];
        else       v = W1[((l - 2) * RANK + r) * NUM_FIELDS + f];
    }
    Wb[i] = (__bf16)v;
}

// ---------------------------------------------------------------------------
// Main: one workgroup (256 thr = 4 waves) per batch element.
//   ret[b] = bias + sum_f linear[idx] + sum_{r,d} dp0*dp1 + sum_{r,d} dp2*dp3*dp4
//   dp_l[r,d] = sum_f W[l,r,f] * emb[b,f,d]   via mfma_f32_16x16x32_bf16
// ---------------------------------------------------------------------------
__global__ __launch_bounds__(256) void tfm_main(const int* __restrict__ x,
                                                const float* __restrict__ embed_table,
                                                const float* __restrict__ linear_table,
                                                const float* __restrict__ bias,
                                                const __bf16* __restrict__ Wb,
                                                float* __restrict__ out,
                                                int out_size) {
    __shared__ int   sidx[NUM_FIELDS];
    __shared__ __align__(16) __bf16 eT[EMBED_DIM * LDS_STRIDE];  // eT[d][f], 18432 B
    __shared__ float wpart[4];

    const int tid = threadIdx.x;
    const int b   = blockIdx.x;

    if (tid < NUM_FIELDS)
        sidx[tid] = x[b * NUM_FIELDS + tid] + tid * PER_FIELD_VOCAB;
    __syncthreads();

    // Gather emb rows -> LDS transposed bf16. Wave reads 64 consecutive d (coalesced 256B).
    for (int k = tid; k < NUM_FIELDS * EMBED_DIM; k += 256) {
        int f = k >> 7, d = k & (EMBED_DIM - 1);
        float v = embed_table[(long)sidx[f] * EMBED_DIM + d];
        eT[d * LDS_STRIDE + f] = (__bf16)v;
    }
    // Zero the K-pad rows f in [39,64) so MFMA pad contributes exactly 0 (no NaN risk).
    for (int k = tid; k < (KPAD - NUM_FIELDS) * EMBED_DIM; k += 256) {
        int f = NUM_FIELDS + (k >> 7), d = k & (EMBED_DIM - 1);
        eT[d * LDS_STRIDE + f] = (__bf16)0.f;
    }

    // Linear term folded into the per-thread partial before the block reduce.
    float partial = 0.f;
    if (tid < NUM_FIELDS) partial = linear_table[sidx[tid]];

    __syncthreads();

    const int wave = tid >> 6, lane = tid & 63;
    const int m = lane & 15, quad = lane >> 4;   // MFMA A/B fragment lane coords

    // Wave w owns r-tiles {2w, 2w+1}; all 8 d-tiles. 16x16 tiles, K=64 (2 chunks of 32).
    for (int rti = 0; rti < 2; ++rti) {
        const int r0 = (wave * 2 + rti) * 16;
        bf16x8 afrag[NL][2];
#pragma unroll
        for (int l = 0; l < NL; ++l)
#pragma unroll
            for (int kc = 0; kc < 2; ++kc)
                afrag[l][kc] = *reinterpret_cast<const bf16x8*>(
                    &Wb[((size_t)(l * RANK) + r0 + m) * KPAD + kc * 32 + quad * 8]);

        for (int dt = 0; dt < 8; ++dt) {
            const int d0 = dt * 16;
            bf16x8 bfrag[2];
#pragma unroll
            for (int kc = 0; kc < 2; ++kc)
                bfrag[kc] = *reinterpret_cast<const bf16x8*>(
                    &eT[(d0 + m) * LDS_STRIDE + kc * 32 + quad * 8]);

            f32x4 acc[NL];
#pragma unroll
            for (int l = 0; l < NL; ++l) {
                acc[l] = (f32x4){0.f, 0.f, 0.f, 0.f};
#pragma unroll
                for (int kc = 0; kc < 2; ++kc)
                    acc[l] = __builtin_amdgcn_mfma_f32_16x16x32_bf16(
                        afrag[l][kc], bfrag[kc], acc[l], 0, 0, 0);
            }
            // dp0*dp1 (W0 pair) + dp2*dp3*dp4 (W1 triple): same C/D layout in all accs,
            // and we reduce over ALL (r,d), so the epilogue is layout-agnostic.
#pragma unroll
            for (int i = 0; i < 4; ++i)
                partial += acc[0][i] * acc[1][i] + acc[2][i] * acc[3][i] * acc[4][i];
        }
    }

    // Block reduction: wave shuffle -> LDS -> thread 0.
#pragma unroll
    for (int off = 32; off > 0; off >>= 1)
        partial += __shfl_down(partial, off, 64);
    if (lane == 0) wpart[wave] = partial;
    __syncthreads();
    if (tid == 0)
        out[b] = wpart[0] + wpart[1] + wpart[2] + wpart[3] + bias[0];

    // Second tuple output ("0") and any trailing pad.
    if (b == 0)
        for (int j = BATCH + tid; j < out_size; j += 256)
            out[j] = 0.f;
}

extern "C" void kernel_launch(void* const* d_in, const int* in_sizes, int n_in,
                              void* d_out, int out_size, void* d_ws, size_t ws_size,
                              hipStream_t stream) {
    const int*   x            = (const int*)d_in[0];
    const float* embed_table  = (const float*)d_in[1];
    const float* linear_table = (const float*)d_in[2];
    const float* bias         = (const float*)d_in[3];
    const float* W0           = (const float*)d_in[4];
    const float* W1           = (const float*)d_in[5];
    __bf16*      Wb           = (__bf16*)d_ws;   // 40960 * 2 B = 80 KB scratch

    prep_w<<<(NL * RANK * KPAD + 255) / 256, 256, 0, stream>>>(W0, W1, Wb);
    tfm_main<<<BATCH, 256, 0, stream>>>(x, embed_table, linear_table, bias, Wb,
                                        (float*)d_out, out_size);
}